// Round 15
// baseline (210.473 us; speedup 1.0000x reference)
//
#include <hip/hip_runtime.h>
#include <stdint.h>

#define NANCH 138240      // 15 * 96 * 96
#define NANCH4 34560      // NANCH / 4
#define B_CNT 32
#define PRE 1024
#define POST 256
#define BINS 8192         // 13-bit exact-key prefix histogram (local)
#define CAP 4096          // cand slots per batch (15 runs of 273 + 1 pad)
#define SBLK 15           // slices per batch
#define SLICE4 2304       // float4 groups per slice (15*2304*4 == 138240)
#define TLOC 192          // local rank target (global share ~68 +- 8; 15 sigma)
#define LOCCAP 273        // per-slice sorted run length (15*273 == 4095)
#define SORTN 512         // in-select bitonic size (pow2 >= LOCCAP)
#define SMROW 17          // padded mask row stride in u64 (bank-conflict fix)
#define PAD_KEY 0xFFFFFFFFFFFFFFFFull

typedef unsigned long long u64;

// descending-value sortable key (ascending uint = descending float)
__device__ __forceinline__ unsigned key32(float sc) {
    unsigned u = __float_as_uint(sc);
    unsigned s = (u & 0x80000000u) ? ~u : (u | 0x80000000u);
    return ~s;
}

// exact log_softmax[1] key — float ops identical to the reference
__device__ __forceinline__ unsigned key_of(float x0, float x1) {
    float m  = fmaxf(x0, x1);
    float e0 = expf(x0 - m);
    float e1 = expf(x1 - m);
    float sc = (x1 - m) - logf(e0 + e1);
    return key32(sc);
}

// IoU > 0.7 test, op-order identical to the reference (no FMA contraction)
__device__ __forceinline__ bool iou_gt(float x1, float y1, float x2, float y2, float ar,
                                       float ox1, float oy1, float ox2, float oy2, float oar) {
    float ix1 = fmaxf(x1, ox1);
    float iy1 = fmaxf(y1, oy1);
    float ix2 = fminf(x2, ox2);
    float iy2 = fminf(y2, oy2);
    float iw = fmaxf(__fadd_rn(__fsub_rn(ix2, ix1), 1.0f), 0.0f);
    float ih = fmaxf(__fadd_rn(__fsub_rn(iy2, iy1), 1.0f), 0.0f);
    float inter = __fmul_rn(iw, ih);
    float denom = __fsub_rn(__fadd_rn(ar, oar), inter);
    return __fdiv_rn(inter, denom) > 0.7f;
}

// ---- box decode (no FMA contraction; matches numpy fp32 op-for-op) --------
__device__ __forceinline__ void decode_box(const float* __restrict__ reg,
                                           const float* __restrict__ anch,
                                           int b, int idx, float box[4]) {
    const float* rb = reg + (size_t)b * 4 * NANCH;
    float dx = rb[idx];
    float dy = rb[idx + NANCH];
    float dw = rb[idx + 2 * NANCH];
    float dh = rb[idx + 3 * NANCH];
    float ax1 = anch[idx * 4 + 0], ay1 = anch[idx * 4 + 1];
    float ax2 = anch[idx * 4 + 2], ay2 = anch[idx * 4 + 3];
    float aw  = __fadd_rn(__fsub_rn(ax2, ax1), 1.0f);
    float ah  = __fadd_rn(__fsub_rn(ay2, ay1), 1.0f);
    float acx = __fadd_rn(ax1, __fmul_rn(0.5f, aw));
    float acy = __fadd_rn(ay1, __fmul_rn(0.5f, ah));
    float pcx = __fadd_rn(__fmul_rn(dx, aw), acx);
    float pcy = __fadd_rn(__fmul_rn(dy, ah), acy);
    float pw  = __fmul_rn(expf(dw), aw);
    float ph  = __fmul_rn(expf(dh), ah);
    float hx  = __fmul_rn(0.5f, pw);
    float hy  = __fmul_rn(0.5f, ph);
    box[0] = fminf(fmaxf(__fsub_rn(pcx, hx), 0.0f), 767.0f);
    box[1] = fminf(fmaxf(__fsub_rn(pcy, hy), 0.0f), 767.0f);
    box[2] = fminf(fmaxf(__fadd_rn(pcx, hx), 0.0f), 767.0f);
    box[3] = fminf(fmaxf(__fadd_rn(pcy, hy), 0.0f), 767.0f);
}

// ---- 64-bit wave shuffles -------------------------------------------------
__device__ __forceinline__ u64 shfl_xor_u64(u64 v, int lanemask) {
    int lo = __shfl_xor((int)(v & 0xFFFFFFFFull), lanemask);
    int hi = __shfl_xor((int)(v >> 32), lanemask);
    return ((u64)(unsigned)hi << 32) | (unsigned)lo;
}
__device__ __forceinline__ u64 shfl_u64(u64 v, int srcLane) {
    int lo = __shfl((int)(v & 0xFFFFFFFFull), srcLane);
    int hi = __shfl((int)(v >> 32), srcLane);
    return ((u64)(unsigned)hi << 32) | (unsigned)lo;
}

// ---- stage 1: one-pass selection; keys cached in registers; sorted emit ---
__global__ __launch_bounds__(1024) void select_kernel(const float* __restrict__ cls,
                                                      u64* __restrict__ cand) {
    __shared__ unsigned h[BINS];        // 32 KB
    __shared__ u64 sortbuf[SORTN];      // 4 KB
    __shared__ unsigned s_wsum[16];
    __shared__ int s_b;
    __shared__ int lcnt;
    const int b = blockIdx.y;
    const int s = blockIdx.x;
    const int t = threadIdx.x;
    const int lane = t & 63, wid = t >> 6;
    if (t == 0) lcnt = 0;
    for (int i = t; i < BINS; i += 1024) h[i] = 0;
    if (t < SORTN) sortbuf[t] = PAD_KEY;
    __syncthreads();

    const float4* cb4 = (const float4*)(cls + (size_t)b * 2 * NANCH);
    const int base4 = s * SLICE4;

    // pass A: compute keys once (held in registers), histogram prefix
    unsigned kk[3][4];
    #pragma unroll
    for (int k = 0; k < 3; ++k) {
        int off = k * 1024 + t;
        if (off < SLICE4) {
            int g4 = base4 + off;
            float4 a0 = cb4[g4];
            float4 a1 = cb4[g4 + NANCH4];
            kk[k][0] = key_of(a0.x, a1.x);
            kk[k][1] = key_of(a0.y, a1.y);
            kk[k][2] = key_of(a0.z, a1.z);
            kk[k][3] = key_of(a0.w, a1.w);
            atomicAdd(&h[kk[k][0] >> 19], 1u);
            atomicAdd(&h[kk[k][1] >> 19], 1u);
            atomicAdd(&h[kk[k][2] >> 19], 1u);
            atomicAdd(&h[kk[k][3] >> 19], 1u);
        }
    }
    __syncthreads();

    // scan: 8 bins/thread segment sums; wave shfl-scan + 16-partial fixup
    unsigned bin[8];
    unsigned seg = 0;
    #pragma unroll
    for (int i = 0; i < 8; ++i) { bin[i] = h[t * 8 + i]; seg += bin[i]; }
    unsigned sc = seg;
    #pragma unroll
    for (int o = 1; o < 64; o <<= 1) {
        unsigned v = (unsigned)__shfl_up((int)sc, o);
        if (lane >= o) sc += v;
    }
    if (lane == 63) s_wsum[wid] = sc;
    __syncthreads();
    unsigned woff = 0;
    for (int i = 0; i < wid; ++i) woff += s_wsum[i];
    unsigned incl = sc + woff;
    unsigned excl = incl - seg;
    if (incl >= TLOC && excl < TLOC) {
        unsigned cum = excl;
        int bs = t * 8 + 7;
        for (int i = 0; i < 8; ++i) {
            if (cum + bin[i] >= TLOC) { bs = t * 8 + i; break; }
            cum += bin[i];
        }
        s_b = bs;
    }
    __syncthreads();
    const int bs = s_b;

    // pass B: test register keys (no cls re-read), scatter into sortbuf
    #pragma unroll
    for (int k = 0; k < 3; ++k) {
        int off = k * 1024 + t;
        if (off < SLICE4) {
            int g4 = base4 + off;
            #pragma unroll
            for (int j = 0; j < 4; ++j) {
                unsigned key = kk[k][j];
                if ((int)(key >> 19) <= bs) {
                    int pos = atomicAdd(&lcnt, 1);
                    if (pos < LOCCAP)
                        sortbuf[pos] = ((u64)key << 32) | (unsigned)(g4 * 4 + j);
                }
            }
        }
    }
    __syncthreads();

    // in-block bitonic sort of 512 slots (real keys first, pads at end)
    for (int k = 2; k <= SORTN; k <<= 1) {
        for (int j = k >> 1; j > 0; j >>= 1) {
            if (t < SORTN / 2) {
                int i = ((t & ~(j - 1)) << 1) | (t & (j - 1));
                int p = i | j;
                bool up = ((i & k) == 0);
                u64 a = sortbuf[i], bb = sortbuf[p];
                if ((a > bb) == up) { sortbuf[i] = bb; sortbuf[p] = a; }
            }
            __syncthreads();
        }
    }

    u64* segp = cand + (size_t)b * CAP + s * LOCCAP;
    for (int i = t; i < LOCCAP; i += 1024) segp[i] = sortbuf[i];
    if (s == 0 && t == 0) cand[(size_t)b * CAP + (CAP - 1)] = PAD_KEY;
}

// ---- stage 2: 15-way rank-merge, 8 blocks/batch, direct scatter -----------
__global__ __launch_bounds__(512) void merge_kernel(const u64* __restrict__ cand,
                                                    const float* __restrict__ reg,
                                                    const float* __restrict__ anch,
                                                    float* __restrict__ topS,
                                                    float* __restrict__ topB) {
    __shared__ u64 runs[CAP];    // 32 KB
    const int b = blockIdx.y;
    const int t = threadIdx.x;   // 0..511
    const int slot = blockIdx.x * 512 + t;   // 0..4095
    for (int i = t; i < CAP; i += 512) runs[i] = cand[(size_t)b * CAP + i];
    __syncthreads();

    u64 x = runs[slot];
    if (x == PAD_KEY) return;            // pads (incl. slot 4095) never emit
    const int r = slot / LOCCAP;         // own run
    int rank = slot - r * LOCCAP;        // position within own sorted run
    for (int q = 0; q < SBLK; ++q) {
        if (q == r) continue;
        const u64* run = &runs[q * LOCCAP];
        int lo = 0, hi = LOCCAP;
        while (lo < hi) {                // lower_bound (9 steps)
            int mid = (lo + hi) >> 1;
            if (run[mid] < x) lo = mid + 1; else hi = mid;
        }
        rank += lo;
    }
    if (rank < PRE) {
        int idx = (int)(x & 0xFFFFFFFFu);
        unsigned ks = (unsigned)(x >> 32);
        unsigned s  = ~ks;
        unsigned u  = (s & 0x80000000u) ? (s & 0x7FFFFFFFu) : ~s;
        float scv = __uint_as_float(u);
        float box[4];
        decode_box(reg, anch, b, idx, box);
        topS[b * PRE + rank] = scv;
        float* tb = topB + ((size_t)b * PRE + rank) * 4;
        tb[0] = box[0]; tb[1] = box[1]; tb[2] = box[2]; tb[3] = box[3];
    }
}

// ---- stage 3: fused mask-in-LDS + barrier-free serial greedy NMS ----------
// Phase 1 (1024 thr): full triangular IoU mask into LDS (padded rows).
// Phase 2 (wave 0 only, zero barriers): greedy scan; rem[] in wave registers
// (lane l owns word l, moved via shfl). Phase 3: write output.
__global__ __launch_bounds__(1024) void nms_kernel(const float* __restrict__ topS,
                                                   const float* __restrict__ topB,
                                                   float* __restrict__ out) {
    __shared__ u64 smask[PRE * SMROW];                               // 136 KB
    __shared__ float sx1[PRE], sy1[PRE], sx2[PRE], sy2[PRE], sar[PRE]; // 20 KB
    __shared__ int kept[POST];
    __shared__ int s_nk;
    const int b = blockIdx.x;
    const int t = threadIdx.x;   // 0..1023

    float4 bx = ((const float4*)topB)[(size_t)b * PRE + t];
    sx1[t] = bx.x; sy1[t] = bx.y; sx2[t] = bx.z; sy2[t] = bx.w;
    sar[t] = __fmul_rn(__fadd_rn(__fsub_rn(bx.z, bx.x), 1.0f),
                       __fadd_rn(__fsub_rn(bx.w, bx.y), 1.0f));
    __syncthreads();

    // phase 1: row t's 16 mask words (triangular: only words w >= t/64 live)
    {
        float x1 = sx1[t], y1 = sy1[t], x2 = sx2[t], y2 = sy2[t], ar = sar[t];
        const int wlo = t >> 6;
        for (int w = 0; w < 16; ++w) {
            u64 m = 0ull;
            if (w >= wlo) {
                const int jbase = w * 64;
                for (int j = 0; j < 64; ++j) {
                    int jj = jbase + j;
                    if (jj > t && iou_gt(x1, y1, x2, y2, ar,
                                         sx1[jj], sy1[jj], sx2[jj], sy2[jj], sar[jj]))
                        m |= (1ull << j);
                }
            }
            smask[t * SMROW + w] = m;
        }
    }
    __syncthreads();

    // phase 2: wave 0 only; no block barriers (all cross-lane via shfl)
    if (t < 64) {
        const int lane = t;
        const int w = lane >> 2, g = lane & 3;
        u64 remreg = 0ull;           // lane l (<16) owns removed-word l
        int prefix = 0;
        for (int c = 0; c < 16; ++c) {
            u64 alive = ~shfl_u64(remreg, c);
            u64 dv = smask[(c * 64 + lane) * SMROW + c];
            int dlo = (int)(dv & 0xFFFFFFFFull);
            int dhi = (int)(dv >> 32);
            for (int l = 0; l < 64; ++l) {
                unsigned lo = (unsigned)__builtin_amdgcn_readlane(dlo, l);
                unsigned hi = (unsigned)__builtin_amdgcn_readlane(dhi, l);
                u64 dl = ((u64)hi << 32) | lo;
                u64 a = (alive >> l) & 1ull;
                alive &= ~(a ? dl : 0ull);
            }
            if ((alive >> lane) & 1ull) {
                int pos = prefix + (int)__popcll(alive & ((1ull << lane) - 1ull));
                if (pos < POST) kept[pos] = c * 64 + lane;
            }
            prefix += (int)__popcll(alive);

            // cross-chunk OR: role (w,g); acc over kept rows g*16..g*16+15
            u64 acc = 0ull;
            #pragma unroll
            for (int k = 0; k < 16; ++k)
                if ((alive >> (g * 16 + k)) & 1ull)
                    acc |= smask[(c * 64 + g * 16 + k) * SMROW + w];
            acc |= shfl_xor_u64(acc, 1);
            acc |= shfl_xor_u64(acc, 2);
            u64 val = shfl_u64(acc, (lane & 15) * 4);  // lane l gets word l's OR
            if (lane < 16 && lane > c) remreg |= val;

            if (prefix >= POST) break;
        }
        if (lane == 0) s_nk = (prefix < POST) ? prefix : POST;
    }
    __syncthreads();

    const int n = s_nk;
    float* ob = out + (size_t)b * POST * 5;
    if (t < POST) {
        if (t < n) {
            int i = kept[t];
            ob[t * 5 + 0] = topS[b * PRE + i];
            ob[t * 5 + 1] = sx1[i];
            ob[t * 5 + 2] = sy1[i];
            ob[t * 5 + 3] = sx2[i];
            ob[t * 5 + 4] = sy2[i];
        } else {
            ob[t * 5 + 0] = 0.0f; ob[t * 5 + 1] = 0.0f; ob[t * 5 + 2] = 0.0f;
            ob[t * 5 + 3] = 0.0f; ob[t * 5 + 4] = 0.0f;
        }
    }
}

extern "C" void kernel_launch(void* const* d_in, const int* in_sizes, int n_in,
                              void* d_out, int out_size, void* d_ws, size_t ws_size,
                              hipStream_t stream) {
    const float* cls  = (const float*)d_in[0];
    const float* reg  = (const float*)d_in[1];
    const float* anch = (const float*)d_in[2];

    // workspace layout (~1.7 MB; everything fully rewritten every launch):
    //   [0,       131072)  topS  32*1024 f32
    //   [131072,  655360)  topB  32*1024*4 f32
    //   [655360,  1703936) cand  32*4096 u64 (15 sorted runs of 273 + pad)
    char* ws = (char*)d_ws;
    float* topS  = (float*)ws;
    float* topB  = (float*)(ws + 131072);
    u64*   cand  = (u64*)(ws + 655360);

    select_kernel<<<dim3(SBLK, B_CNT), 1024, 0, stream>>>(cls, cand);
    merge_kernel <<<dim3(8, B_CNT), 512, 0, stream>>>(cand, reg, anch, topS, topB);
    nms_kernel   <<<B_CNT, 1024, 0, stream>>>(topS, topB, (float*)d_out);
}

// Round 16
// 83.755 us; speedup vs baseline: 2.5130x; 2.5130x over previous
//
#include <hip/hip_runtime.h>
#include <stdint.h>

#define NANCH 138240      // 15 * 96 * 96
#define NANCH4 34560      // NANCH / 4
#define B_CNT 32
#define PRE 1024
#define POST 256
#define BINS 8192         // 13-bit exact-key prefix histogram (local)
#define CAP 4096          // cand slots per batch (15 runs of 273 + 1 pad)
#define SBLK 15           // slices per batch
#define SLICE4 2304       // float4 groups per slice (15*2304*4 == 138240)
#define TLOC 192          // local rank target (global share ~68 +- 8; 15 sigma)
#define LOCCAP 273        // per-slice sorted run length (15*273 == 4095)
#define SORTN 512         // in-select bitonic size (pow2 >= LOCCAP)
#define PAD_KEY 0xFFFFFFFFFFFFFFFFull

typedef unsigned long long u64;

// descending-value sortable key (ascending uint = descending float)
__device__ __forceinline__ unsigned key32(float sc) {
    unsigned u = __float_as_uint(sc);
    unsigned s = (u & 0x80000000u) ? ~u : (u | 0x80000000u);
    return ~s;
}

// exact log_softmax[1] key — float ops identical to the reference
__device__ __forceinline__ unsigned key_of(float x0, float x1) {
    float m  = fmaxf(x0, x1);
    float e0 = expf(x0 - m);
    float e1 = expf(x1 - m);
    float sc = (x1 - m) - logf(e0 + e1);
    return key32(sc);
}

// ---- box decode (no FMA contraction; matches numpy fp32 op-for-op) --------
__device__ __forceinline__ void decode_box(const float* __restrict__ reg,
                                           const float* __restrict__ anch,
                                           int b, int idx, float box[4]) {
    const float* rb = reg + (size_t)b * 4 * NANCH;
    float dx = rb[idx];
    float dy = rb[idx + NANCH];
    float dw = rb[idx + 2 * NANCH];
    float dh = rb[idx + 3 * NANCH];
    float ax1 = anch[idx * 4 + 0], ay1 = anch[idx * 4 + 1];
    float ax2 = anch[idx * 4 + 2], ay2 = anch[idx * 4 + 3];
    float aw  = __fadd_rn(__fsub_rn(ax2, ax1), 1.0f);
    float ah  = __fadd_rn(__fsub_rn(ay2, ay1), 1.0f);
    float acx = __fadd_rn(ax1, __fmul_rn(0.5f, aw));
    float acy = __fadd_rn(ay1, __fmul_rn(0.5f, ah));
    float pcx = __fadd_rn(__fmul_rn(dx, aw), acx);
    float pcy = __fadd_rn(__fmul_rn(dy, ah), acy);
    float pw  = __fmul_rn(expf(dw), aw);
    float ph  = __fmul_rn(expf(dh), ah);
    float hx  = __fmul_rn(0.5f, pw);
    float hy  = __fmul_rn(0.5f, ph);
    box[0] = fminf(fmaxf(__fsub_rn(pcx, hx), 0.0f), 767.0f);
    box[1] = fminf(fmaxf(__fsub_rn(pcy, hy), 0.0f), 767.0f);
    box[2] = fminf(fmaxf(__fadd_rn(pcx, hx), 0.0f), 767.0f);
    box[3] = fminf(fmaxf(__fadd_rn(pcy, hy), 0.0f), 767.0f);
}

// ---- stage 1: one-pass selection; keys cached in registers; sorted emit ---
__global__ __launch_bounds__(1024) void select_kernel(const float* __restrict__ cls,
                                                      u64* __restrict__ cand) {
    __shared__ unsigned h[BINS];        // 32 KB
    __shared__ u64 sortbuf[SORTN];      // 4 KB
    __shared__ unsigned s_wsum[16];
    __shared__ int s_b;
    __shared__ int lcnt;
    const int b = blockIdx.y;
    const int s = blockIdx.x;
    const int t = threadIdx.x;
    const int lane = t & 63, wid = t >> 6;
    if (t == 0) lcnt = 0;
    for (int i = t; i < BINS; i += 1024) h[i] = 0;
    if (t < SORTN) sortbuf[t] = PAD_KEY;
    __syncthreads();

    const float4* cb4 = (const float4*)(cls + (size_t)b * 2 * NANCH);
    const int base4 = s * SLICE4;

    // pass A: compute keys once (held in registers), histogram prefix
    unsigned kk[3][4];
    #pragma unroll
    for (int k = 0; k < 3; ++k) {
        int off = k * 1024 + t;
        if (off < SLICE4) {
            int g4 = base4 + off;
            float4 a0 = cb4[g4];
            float4 a1 = cb4[g4 + NANCH4];
            kk[k][0] = key_of(a0.x, a1.x);
            kk[k][1] = key_of(a0.y, a1.y);
            kk[k][2] = key_of(a0.z, a1.z);
            kk[k][3] = key_of(a0.w, a1.w);
            atomicAdd(&h[kk[k][0] >> 19], 1u);
            atomicAdd(&h[kk[k][1] >> 19], 1u);
            atomicAdd(&h[kk[k][2] >> 19], 1u);
            atomicAdd(&h[kk[k][3] >> 19], 1u);
        }
    }
    __syncthreads();

    // scan: 8 bins/thread segment sums; wave shfl-scan + 16-partial fixup
    unsigned bin[8];
    unsigned seg = 0;
    #pragma unroll
    for (int i = 0; i < 8; ++i) { bin[i] = h[t * 8 + i]; seg += bin[i]; }
    unsigned sc = seg;
    #pragma unroll
    for (int o = 1; o < 64; o <<= 1) {
        unsigned v = (unsigned)__shfl_up((int)sc, o);
        if (lane >= o) sc += v;
    }
    if (lane == 63) s_wsum[wid] = sc;
    __syncthreads();
    unsigned woff = 0;
    for (int i = 0; i < wid; ++i) woff += s_wsum[i];
    unsigned incl = sc + woff;
    unsigned excl = incl - seg;
    if (incl >= TLOC && excl < TLOC) {
        unsigned cum = excl;
        int bs = t * 8 + 7;
        for (int i = 0; i < 8; ++i) {
            if (cum + bin[i] >= TLOC) { bs = t * 8 + i; break; }
            cum += bin[i];
        }
        s_b = bs;
    }
    __syncthreads();
    const int bs = s_b;

    // pass B: test register keys (no cls re-read), scatter into sortbuf
    #pragma unroll
    for (int k = 0; k < 3; ++k) {
        int off = k * 1024 + t;
        if (off < SLICE4) {
            int g4 = base4 + off;
            #pragma unroll
            for (int j = 0; j < 4; ++j) {
                unsigned key = kk[k][j];
                if ((int)(key >> 19) <= bs) {
                    int pos = atomicAdd(&lcnt, 1);
                    if (pos < LOCCAP)
                        sortbuf[pos] = ((u64)key << 32) | (unsigned)(g4 * 4 + j);
                }
            }
        }
    }
    __syncthreads();

    // in-block bitonic sort of 512 slots (real keys first, pads at end)
    for (int k = 2; k <= SORTN; k <<= 1) {
        for (int j = k >> 1; j > 0; j >>= 1) {
            if (t < SORTN / 2) {
                int i = ((t & ~(j - 1)) << 1) | (t & (j - 1));
                int p = i | j;
                bool up = ((i & k) == 0);
                u64 a = sortbuf[i], bb = sortbuf[p];
                if ((a > bb) == up) { sortbuf[i] = bb; sortbuf[p] = a; }
            }
            __syncthreads();
        }
    }

    u64* segp = cand + (size_t)b * CAP + s * LOCCAP;
    for (int i = t; i < LOCCAP; i += 1024) segp[i] = sortbuf[i];
    if (s == 0 && t == 0) cand[(size_t)b * CAP + (CAP - 1)] = PAD_KEY;
}

// ---- stage 2: 15-way rank-merge, 8 blocks/batch, direct scatter -----------
// cand = 15 sorted runs of 273 (+1 pad slot). Non-pad keys distinct -> ranks
// form a permutation; pads (equal 0xFF..) never rank < 1024 (>= 15*192=2880).
__global__ __launch_bounds__(512) void merge_kernel(const u64* __restrict__ cand,
                                                    const float* __restrict__ reg,
                                                    const float* __restrict__ anch,
                                                    float* __restrict__ topS,
                                                    float* __restrict__ topB) {
    __shared__ u64 runs[CAP];    // 32 KB
    const int b = blockIdx.y;
    const int t = threadIdx.x;   // 0..511
    const int slot = blockIdx.x * 512 + t;   // 0..4095
    for (int i = t; i < CAP; i += 512) runs[i] = cand[(size_t)b * CAP + i];
    __syncthreads();

    u64 x = runs[slot];
    if (x == PAD_KEY) return;            // pads (incl. slot 4095) never emit
    const int r = slot / LOCCAP;         // own run
    int rank = slot - r * LOCCAP;        // position within own sorted run
    for (int q = 0; q < SBLK; ++q) {
        if (q == r) continue;
        const u64* run = &runs[q * LOCCAP];
        int lo = 0, hi = LOCCAP;
        while (lo < hi) {                // lower_bound (9 steps)
            int mid = (lo + hi) >> 1;
            if (run[mid] < x) lo = mid + 1; else hi = mid;
        }
        rank += lo;
    }
    if (rank < PRE) {
        int idx = (int)(x & 0xFFFFFFFFu);
        unsigned ks = (unsigned)(x >> 32);
        unsigned s  = ~ks;
        unsigned u  = (s & 0x80000000u) ? (s & 0x7FFFFFFFu) : ~s;
        float scv = __uint_as_float(u);
        float box[4];
        decode_box(reg, anch, b, idx, box);
        topS[b * PRE + rank] = scv;
        float* tb = topB + ((size_t)b * PRE + rank) * 4;
        tb[0] = box[0]; tb[1] = box[1]; tb[2] = box[2]; tb[3] = box[3];
    }
}

// ---- stage 3: suppression bitmask (iou > 0.7 for j > i; triangular) -------
__global__ __launch_bounds__(1024) void mask_kernel(const float* __restrict__ topB,
                                                    u64* __restrict__ masks) {
    const int w = blockIdx.x;   // 64-col chunk: 0..15
    const int b = blockIdx.y;
    const int i = threadIdx.x;  // row 0..1023
    __shared__ float sx1[64], sy1[64], sx2[64], sy2[64], sar[64];
    if (i < 64) {
        const float* p = topB + ((size_t)b * PRE + w * 64 + i) * 4;
        float x1 = p[0], y1 = p[1], x2 = p[2], y2 = p[3];
        sx1[i] = x1; sy1[i] = y1; sx2[i] = x2; sy2[i] = y2;
        sar[i] = __fmul_rn(__fadd_rn(__fsub_rn(x2, x1), 1.0f),
                           __fadd_rn(__fsub_rn(y2, y1), 1.0f));
    }
    __syncthreads();
    const int jbase = w * 64;
    u64* dst = &masks[((size_t)b * PRE + i) * 16 + w];
    if (i >= jbase + 63) { *dst = 0ull; return; }   // upper-triangle only
    const float* p = topB + ((size_t)b * PRE + i) * 4;
    float x1 = p[0], y1 = p[1], x2 = p[2], y2 = p[3];
    float ar = __fmul_rn(__fadd_rn(__fsub_rn(x2, x1), 1.0f),
                         __fadd_rn(__fsub_rn(y2, y1), 1.0f));
    u64 m = 0ull;
    for (int j = 0; j < 64; j++) {
        int jj = jbase + j;
        if (jj > i) {
            float ix1 = fmaxf(x1, sx1[j]);
            float iy1 = fmaxf(y1, sy1[j]);
            float ix2 = fminf(x2, sx2[j]);
            float iy2 = fminf(y2, sy2[j]);
            float iw = fmaxf(__fadd_rn(__fsub_rn(ix2, ix1), 1.0f), 0.0f);
            float ih = fmaxf(__fadd_rn(__fsub_rn(iy2, iy1), 1.0f), 0.0f);
            float inter = __fmul_rn(iw, ih);
            float denom = __fsub_rn(__fadd_rn(ar, sar[j]), inter);
            float iou = __fdiv_rn(inter, denom);
            if (iou > 0.7f) m |= (1ull << j);
        }
    }
    *dst = m;
}

// ---- 64-bit helpers over wave --------------------------------------------
__device__ __forceinline__ u64 shfl_xor_u64(u64 v, int lanemask) {
    int lo = __shfl_xor((int)(v & 0xFFFFFFFFull), lanemask);
    int hi = __shfl_xor((int)(v >> 32), lanemask);
    return ((u64)(unsigned)hi << 32) | (unsigned)lo;
}

// ---- stage 4: pipelined chunked greedy NMS with early exit ----------------
__global__ __launch_bounds__(64) void nms_kernel(const u64* __restrict__ masks,
                                                 const float* __restrict__ topS,
                                                 const float* __restrict__ topB,
                                                 float* __restrict__ out) {
    const int b = blockIdx.x;
    const int t = threadIdx.x;      // 0..63
    __shared__ u64 rem[16];
    __shared__ int kept[POST];
    __shared__ int s_nk;
    if (t < 16) rem[t] = 0ull;
    __syncthreads();

    const u64* mb = masks + (size_t)b * PRE * 16;
    const int w = t >> 2, g = t & 3;   // cross-chunk role: word w, row-group g
    int prefix = 0;

    // prefetch chunk 0
    u64 dv_cur = mb[(size_t)t * 16 + 0];
    u64 cw_cur[16];
    #pragma unroll
    for (int k = 0; k < 16; ++k)
        cw_cur[k] = mb[((size_t)(g * 16 + k)) * 16 + w];

    for (int c = 0; c < 16; ++c) {
        u64 dv_nxt = 0ull;
        u64 cw_nxt[16];
        if (c < 15) {
            const u64* nb = mb + (size_t)(c + 1) * 64 * 16;
            dv_nxt = nb[(size_t)t * 16 + (c + 1)];
            #pragma unroll
            for (int k = 0; k < 16; ++k)
                cw_nxt[k] = nb[((size_t)(g * 16 + k)) * 16 + w];
        } else {
            #pragma unroll
            for (int k = 0; k < 16; ++k) cw_nxt[k] = 0ull;
        }

        u64 alive = ~rem[c];
        int dlo = (int)(dv_cur & 0xFFFFFFFFull);
        int dhi = (int)(dv_cur >> 32);

        for (int l = 0; l < 64; ++l) {
            unsigned lo = (unsigned)__builtin_amdgcn_readlane(dlo, l);
            unsigned hi = (unsigned)__builtin_amdgcn_readlane(dhi, l);
            u64 dl = ((u64)hi << 32) | lo;
            u64 a = (alive >> l) & 1ull;
            alive &= ~(a ? dl : 0ull);
        }

        if ((alive >> t) & 1ull) {
            int pos = prefix + (int)__popcll(alive & ((1ull << t) - 1ull));
            if (pos < POST) kept[pos] = c * 64 + t;
        }
        prefix += (int)__popcll(alive);

        u64 acc = 0ull;
        #pragma unroll
        for (int k = 0; k < 16; ++k)
            if ((alive >> (g * 16 + k)) & 1ull) acc |= cw_cur[k];
        acc |= shfl_xor_u64(acc, 1);
        acc |= shfl_xor_u64(acc, 2);
        __syncthreads();
        if (g == 0 && w > c) rem[w] |= acc;
        __syncthreads();

        if (prefix >= POST) break;   // first POST kept found; rest irrelevant

        dv_cur = dv_nxt;
        #pragma unroll
        for (int k = 0; k < 16; ++k) cw_cur[k] = cw_nxt[k];
    }

    if (t == 0) s_nk = (prefix < POST) ? prefix : POST;
    __syncthreads();
    const int n = s_nk;

    float* ob = out + (size_t)b * POST * 5;
    for (int r = t; r < POST; r += 64) {
        if (r < n) {
            int i = kept[r];
            ob[r * 5 + 0] = topS[b * PRE + i];
            const float* tb = topB + ((size_t)b * PRE + i) * 4;
            ob[r * 5 + 1] = tb[0];
            ob[r * 5 + 2] = tb[1];
            ob[r * 5 + 3] = tb[2];
            ob[r * 5 + 4] = tb[3];
        } else {
            ob[r * 5 + 0] = 0.0f; ob[r * 5 + 1] = 0.0f; ob[r * 5 + 2] = 0.0f;
            ob[r * 5 + 3] = 0.0f; ob[r * 5 + 4] = 0.0f;
        }
    }
}

extern "C" void kernel_launch(void* const* d_in, const int* in_sizes, int n_in,
                              void* d_out, int out_size, void* d_ws, size_t ws_size,
                              hipStream_t stream) {
    const float* cls  = (const float*)d_in[0];
    const float* reg  = (const float*)d_in[1];
    const float* anch = (const float*)d_in[2];

    // workspace layout (~5.9 MB; everything fully rewritten every launch):
    //   [0,       131072)  topS  32*1024 f32
    //   [131072,  655360)  topB  32*1024*4 f32
    //   [655360,  1703936) cand  32*4096 u64 (15 sorted runs of 273 + pad)
    //   [1703936, 5898240) masks 32*1024*16 u64
    char* ws = (char*)d_ws;
    float* topS  = (float*)ws;
    float* topB  = (float*)(ws + 131072);
    u64*   cand  = (u64*)(ws + 655360);
    u64*   masks = (u64*)(ws + 1703936);

    select_kernel<<<dim3(SBLK, B_CNT), 1024, 0, stream>>>(cls, cand);
    merge_kernel <<<dim3(8, B_CNT), 512, 0, stream>>>(cand, reg, anch, topS, topB);
    mask_kernel  <<<dim3(16, B_CNT), 1024, 0, stream>>>(topB, masks);
    nms_kernel   <<<B_CNT, 64, 0, stream>>>(masks, topS, topB, (float*)d_out);
}